// Round 6
// baseline (395.347 us; speedup 1.0000x reference)
//
#include <hip/hip_runtime.h>
#include <cstdint>
#include <cstddef>

// ---------------- problem constants ----------------
#define DMODEL 1024
#define DINNER 2048
#define DSTATE 16
#define DCONV  4
#define DTRANK 64
#define BSZ    2
#define SEQL   2048
#define MROWS  (BSZ*SEQL)          // 4096
#define NCHUNK 32                  // scan chunks per sequence
#define CLEN   (SEQL/NCHUNK)       // 64

typedef __bf16 bf16;
typedef bf16  bf16x8 __attribute__((ext_vector_type(8)));
typedef bf16  bf16x4 __attribute__((ext_vector_type(4)));
typedef float floatx4 __attribute__((ext_vector_type(4)));

#define EPILDC 136   // padded epilogue LDS leading dim (272B = 4 mod 32 banks)

__device__ __forceinline__ float fsigmoid(float x){ return 1.f/(1.f+__expf(-x)); }
__device__ __forceinline__ float fsilu(float x){ return x*fsigmoid(x); }

__device__ __forceinline__ void gload_lds16(const void* g, void* l){
  __builtin_amdgcn_global_load_lds((__attribute__((address_space(1))) void*)g,
                                   (__attribute__((address_space(3))) void*)l,
                                   16, 0, 0);
}

// ---------------- elementwise cast fp32 -> bf16 (vec4) ----------------
__global__ void k_cast_bf16(const float* __restrict__ in, bf16* __restrict__ out, int n){
  int i = (blockIdx.x*blockDim.x + threadIdx.x)*4;
  if (i < n){
    float4 v = *(const float4*)(in + i);
    bf16x4 o; o[0]=(bf16)v.x; o[1]=(bf16)v.y; o[2]=(bf16)v.z; o[3]=(bf16)v.w;
    *(bf16x4*)(out + i) = o;
  }
}

// ---------------- all 4 weight transposes in ONE launch ----------------
// out[c][r] = in[r][c], zero-pad rows >= C (outR).  block (32,8)
__global__ void k_transpose_all(const float* __restrict__ W_in, const float* __restrict__ W_out,
                                const float* __restrict__ W_xproj, const float* __restrict__ W_dt,
                                bf16* __restrict__ WinT, bf16* __restrict__ WoutT,
                                bf16* __restrict__ WxT, bf16* __restrict__ WdtT){
  __shared__ float tile[32][33];
  int b = blockIdx.x;
  const float* in; bf16* out; int R, C, outR, nbx;
  if      (b < 4096)            { in=W_in;    out=WinT;  R=1024; C=4096; outR=4096; nbx=128; }
  else if (b < 4096+2048)       { b-=4096;    in=W_out;  out=WoutT; R=2048; C=1024; outR=1024; nbx=32; }
  else if (b < 4096+2048+256)   { b-=6144;    in=W_xproj;out=WxT;  R=2048; C=96;   outR=128;  nbx=4; }
  else                          { b-=6400;    in=W_dt;   out=WdtT; R=64;   C=2048; outR=2048; nbx=64; }
  int c0 = (b % nbx)*32, r0 = (b / nbx)*32;
  int tx = threadIdx.x, ty = threadIdx.y;
  #pragma unroll
  for (int ii=0; ii<4; ++ii){
    int r = r0 + ty + ii*8, c = c0 + tx;
    float v = 0.f;
    if (r < R && c < C) v = in[(size_t)r*C + c];
    tile[ty+ii*8][tx] = v;
  }
  __syncthreads();
  #pragma unroll
  for (int ii=0; ii<4; ++ii){
    int orow = c0 + ty + ii*8;   // original col
    int ocol = r0 + tx;          // original row
    if (orow < outR && ocol < R) out[(size_t)orow*R + ocol] = (bf16)tile[tx][ty+ii*8];
  }
}

// ---------------- bf16 MFMA GEMM: C = A(M,K) * B^T(N,K), 128 x (128*NSUB) tile, BK=64 ----
// LDS K-loop tiles (row = 128B = 32 banks). Chunk swizzle: 16B slot s of row r holds
//   global chunk s ^ (r&7) -> ds_read_b128 start banks 2-way (free); staging stays
//   lane-contiguous (global_load_lds constraint) and 128B coalesced.
// NSUB=2 doubles the N-tile: same A-staging feeds 2x the MFMA per barrier drain
//   (the structural stall of this K-loop shape); 48KB LDS, 2 blocks/CU.
// Epilogue (EPI 1/2): per 128-col half, 128x136-padded LDS stage then 16B stores.
// EPI 0: fp32 scattered dword stores to C0 + z*M*N (split-K partials)
// EPI 1: GEMM-in: col<DINNER -> u_pre bf16 (C1); col>=DINNER -> silu -> resb (C2)
// EPI 2: dt: bf16(softplus(acc + bias[col])) -> C1, ldc=N
template<int EPI, int NSUB>
__global__ __launch_bounds__(256)
void k_gemm_bt(const bf16* __restrict__ A, const bf16* __restrict__ Bt,
               int M, int N, int K,
               float* __restrict__ C0, bf16* __restrict__ C1, bf16* __restrict__ C2,
               const float* __restrict__ bias){
  __shared__ bf16 lds[8192*(1+NSUB) > 128*EPILDC ? 8192*(1+NSUB) : 128*EPILDC];
  bf16* ldsA = lds;                      // 128 x 64
  bf16* ldsB = lds + 8192;               // (128*NSUB) x 64
  const int tid  = threadIdx.x;
  const int lane = tid & 63;
  const int wave = tid >> 6;
  const int quad = lane >> 4;
  const int mrow = lane & 15;
  const int wr = wave >> 1, wc = wave & 1;     // 2x2 wave grid
  const int bm = blockIdx.y * 128, bn = blockIdx.x * (128*NSUB);
  const int Ks   = K / gridDim.z;
  const int kbeg = blockIdx.z * Ks;

  floatx4 acc[NSUB][4][4];
  #pragma unroll
  for (int h=0;h<NSUB;++h)
    #pragma unroll
    for (int i=0;i<4;++i)
      #pragma unroll
      for (int j=0;j<4;++j) acc[h][i][j] = (floatx4){0.f,0.f,0.f,0.f};

  // staging: thread t -> row r_local = t>>3 (+p*32), 16B slot t&7 holds global chunk (t&7)^(r&7)
  const int r_local = tid >> 3;
  const int cs = (((tid & 7) ^ (r_local & 7)) * 8);   // element offset of fetched chunk
  const bf16* Abase = A  + (size_t)(bm + r_local) * K + cs;
  const bf16* Bbase = Bt + (size_t)(bn + r_local) * K + cs;
  const int swz = mrow & 7;                    // read-side swizzle key (row&7 == mrow&7)

  for (int k0 = kbeg; k0 < kbeg + Ks; k0 += 64){
    #pragma unroll
    for (int p=0;p<4;++p)
      gload_lds16(Abase + k0 + (size_t)p*32*K, ldsA + (p*256 + tid)*8);
    #pragma unroll
    for (int p=0;p<4*NSUB;++p)
      gload_lds16(Bbase + k0 + (size_t)p*32*K, ldsB + (p*256 + tid)*8);
    __syncthreads();

    #pragma unroll
    for (int kk=0; kk<2; ++kk){
      const int qs = quad + kk*4;              // logical 16B chunk index within row
      bf16x8 af[4], bfr[NSUB][4];
      #pragma unroll
      for (int i=0;i<4;++i)
        af[i] = *(const bf16x8*)(ldsA + (wr*64 + i*16 + mrow)*64 + (qs ^ swz)*8);
      #pragma unroll
      for (int h=0;h<NSUB;++h)
        #pragma unroll
        for (int j=0;j<4;++j)
          bfr[h][j] = *(const bf16x8*)(ldsB + (h*128 + wc*64 + j*16 + mrow)*64 + (qs ^ swz)*8);
      #pragma unroll
      for (int h=0;h<NSUB;++h)
        #pragma unroll
        for (int i=0;i<4;++i)
          #pragma unroll
          for (int j=0;j<4;++j)
            acc[h][i][j] = __builtin_amdgcn_mfma_f32_16x16x32_bf16(af[i], bfr[h][j], acc[h][i][j], 0,0,0);
    }
    __syncthreads();
  }

  // ---- epilogue: lane holds D[row=quad*4+r][col=mrow] of each 16x16 tile ----
  if (EPI == 0){
    float* Cz = C0 + (size_t)blockIdx.z * M * N;
    #pragma unroll
    for (int h=0;h<NSUB;++h)
      #pragma unroll
      for (int i=0;i<4;++i)
        #pragma unroll
        for (int r=0;r<4;++r){
          int row = bm + wr*64 + i*16 + quad*4 + r;
          #pragma unroll
          for (int j=0;j<4;++j){
            int col = bn + h*128 + wc*64 + j*16 + mrow;
            Cz[(size_t)row*N + col] = acc[h][i][j][r];
          }
        }
  } else {
    #pragma unroll
    for (int h=0;h<NSUB;++h){
      if (h) __syncthreads();                  // previous half's stores done reading LDS
      const int bnh = bn + h*128;
      const bool isres = (EPI == 1) && (bnh >= DINNER);
      #pragma unroll
      for (int i=0;i<4;++i)
        #pragma unroll
        for (int r=0;r<4;++r){
          int lrow = wr*64 + i*16 + quad*4 + r;
          #pragma unroll
          for (int j=0;j<4;++j){
            int lcol = wc*64 + j*16 + mrow;
            float v = acc[h][i][j][r];
            float vt;
            if (EPI == 1) vt = isres ? fsilu(v) : v;
            else {
              float z = v + bias[bnh + lcol];
              vt = (z > 20.f) ? z : log1pf(__expf(z));
            }
            lds[lrow*EPILDC + lcol] = (bf16)vt;
          }
        }
      __syncthreads();
      bf16* dst; int ldc;
      if (EPI == 1){ ldc = DINNER; dst = isres ? (C2 + (bnh - DINNER)) : (C1 + bnh); }
      else         { ldc = N;      dst = C1 + bnh; }
      const int rr = tid >> 1, hh = (tid & 1)*64;
      #pragma unroll
      for (int i=0;i<8;++i)
        *(bf16x8*)(dst + (size_t)(bm + rr)*ldc + hh + i*8) =
          *(const bf16x8*)(lds + rr*EPILDC + hh + i*8);
    }
  }
}

// ---------------- split-K reduce for x_dbl (+ fused dt_low bf16 slice cast) ----------------
__global__ void k_xdbl_reduce(const float* __restrict__ part, float* __restrict__ xdbl,
                              bf16* __restrict__ dtlowb){
  int t = blockIdx.x*blockDim.x + threadIdx.x;   // MROWS*128/4 threads
  int i4 = t*4;
  floatx4 acc = (floatx4){0.f,0.f,0.f,0.f};
  #pragma unroll
  for (int z=0; z<8; ++z)
    acc += *(const floatx4*)(part + (size_t)z*MROWS*128 + i4);
  *(floatx4*)(xdbl + i4) = acc;
  int r = i4 >> 7, c = i4 & 127;
  if (c < DTRANK){
    bf16x4 o; o[0]=(bf16)acc[0]; o[1]=(bf16)acc[1]; o[2]=(bf16)acc[2]; o[3]=(bf16)acc[3];
    *(bf16x4*)(dtlowb + (size_t)r*DTRANK + c) = o;
  }
}

// ---------------- split-K=2 reduce for out GEMM (fp32) ----------------
__global__ void k_out_reduce(const float* __restrict__ part, float* __restrict__ out){
  int i4 = (blockIdx.x*blockDim.x + threadIdx.x)*4;
  floatx4 a = *(const floatx4*)(part + i4);
  floatx4 b = *(const floatx4*)(part + (size_t)MROWS*DMODEL + i4);
  *(floatx4*)(out + i4) = a + b;
}

// ---------------- depthwise causal conv (width 4) + bias + SiLU -> bf16, vec4 in d ------
__global__ void k_conv_silu(const bf16* __restrict__ u_pre,
                            const float* __restrict__ conv_w,
                            const float* __restrict__ conv_b,
                            bf16* __restrict__ ub){
  int t   = blockIdx.x*blockDim.x + threadIdx.x;   // MROWS*DINNER/4
  int d4  = (t & (DINNER/4-1))*4;
  int row = t >> 9;
  int l   = row & (SEQL-1);
  float4 cb = *(const float4*)(conv_b + d4);
  float acc[4] = {cb.x, cb.y, cb.z, cb.w};
  float4 w0 = *(const float4*)(conv_w + (d4+0)*4);
  float4 w1 = *(const float4*)(conv_w + (d4+1)*4);
  float4 w2 = *(const float4*)(conv_w + (d4+2)*4);
  float4 w3 = *(const float4*)(conv_w + (d4+3)*4);
  float wk[4][4] = {{w0.x,w0.y,w0.z,w0.w},{w1.x,w1.y,w1.z,w1.w},
                    {w2.x,w2.y,w2.z,w2.w},{w3.x,w3.y,w3.z,w3.w}};
  #pragma unroll
  for (int k=0;k<4;++k){
    int lk = l + k - 3;
    if (lk >= 0){
      bf16x4 uv = *(const bf16x4*)(u_pre + (size_t)(row + k - 3)*DINNER + d4);
      #pragma unroll
      for (int j=0;j<4;++j) acc[j] += (float)uv[j] * wk[j][k];
    }
  }
  bf16x4 o;
  #pragma unroll
  for (int j=0;j<4;++j) o[j] = (bf16)fsilu(acc[j]);
  *(bf16x4*)(ub + (size_t)row*DINNER + d4) = o;
}

// ---------------- scan phase 1: 4 states/thread, per-chunk transfer (P, S) ----------------
__global__ void k_scan_phase1(const bf16* __restrict__ dt, const bf16* __restrict__ ub,
                              const float* __restrict__ x_dbl, const float* __restrict__ A_log,
                              float* __restrict__ Pbuf, float* __restrict__ Sbuf){
  int t  = blockIdx.x*blockDim.x + threadIdx.x;   // BSZ*NCHUNK*DINNER*4 = 524288
  int g  = t & 3;
  int d  = (t >> 2) & (DINNER-1);
  int bc = t >> 13;
  int c  = bc & (NCHUNK-1);
  int b  = bc >> 5;
  floatx4 alog = *(const floatx4*)(A_log + d*DSTATE + g*4);
  float an[4];
  #pragma unroll
  for (int n=0;n<4;++n) an[n] = -__expf(alog[n]);
  float P[4] = {1.f,1.f,1.f,1.f}, S[4] = {0.f,0.f,0.f,0.f};
  int base_row = b*SEQL + c*CLEN;
  for (int s=0;s<CLEN;++s){
    size_t row = base_row + s;
    float dtv = (float)dt[row*DINNER + d];
    float uv  = (float)ub[row*DINNER + d];
    float du  = dtv*uv;
    floatx4 Bv = *(const floatx4*)(x_dbl + row*128 + DTRANK + g*4);
    #pragma unroll
    for (int n=0;n<4;++n){
      float e = __expf(dtv*an[n]);
      P[n] *= e;
      S[n]  = fmaf(S[n], e, du*Bv[n]);
    }
  }
  size_t ob = ((size_t)bc*DINNER + d)*DSTATE + g*4;
  floatx4 Pv = {P[0],P[1],P[2],P[3]}, Sv = {S[0],S[1],S[2],S[3]};
  *(floatx4*)(Pbuf + ob) = Pv;
  *(floatx4*)(Sbuf + ob) = Sv;
}

// ---------------- scan phase 2: chunk combine over (b,d,n); Sbuf <- entry state ----------
__global__ void k_scan_phase2(const float* __restrict__ Pbuf, float* __restrict__ Sbuf){
  int t = blockIdx.x*blockDim.x + threadIdx.x;   // BSZ*DINNER*DSTATE = 65536
  int b   = t >> 15;
  int rem = t & 32767;           // d*16 + n
  float h = 0.f;
  for (int c=0;c<NCHUNK;++c){
    size_t ix = (size_t)(b*NCHUNK + c)*DINNER*DSTATE + rem;
    float p = Pbuf[ix], s = Sbuf[ix];
    Sbuf[ix] = h;                // entry state for chunk c
    h = fmaf(p, h, s);
  }
}

// ---------------- scan phase 3: replay with known entry state; fuse +u*D, *silu(res) -----
__global__ void k_scan_phase3(const bf16* __restrict__ dt, const bf16* __restrict__ ub,
                              const float* __restrict__ x_dbl, const float* __restrict__ A_log,
                              const float* __restrict__ Dvec, const float* __restrict__ Hin,
                              const bf16* __restrict__ resb, bf16* __restrict__ yb){
  int t  = blockIdx.x*blockDim.x + threadIdx.x;
  int g  = t & 3;
  int d  = (t >> 2) & (DINNER-1);
  int bc = t >> 13;
  int c  = bc & (NCHUNK-1);
  int b  = bc >> 5;
  floatx4 alog = *(const floatx4*)(A_log + d*DSTATE + g*4);
  float an[4];
  #pragma unroll
  for (int n=0;n<4;++n) an[n] = -__expf(alog[n]);
  floatx4 h = *(const floatx4*)(Hin + ((size_t)bc*DINNER + d)*DSTATE + g*4);
  float Dd = Dvec[d];
  int base_row = b*SEQL + c*CLEN;
  for (int s=0;s<CLEN;++s){
    size_t row = base_row + s;
    float dtv = (float)dt[row*DINNER + d];
    float uv  = (float)ub[row*DINNER + d];
    float du  = dtv*uv;
    floatx4 Bv = *(const floatx4*)(x_dbl + row*128 + DTRANK + g*4);
    floatx4 Cv = *(const floatx4*)(x_dbl + row*128 + DTRANK + DSTATE + g*4);
    float y = 0.f;
    #pragma unroll
    for (int n=0;n<4;++n){
      float e = __expf(dtv*an[n]);
      h[n] = fmaf(h[n], e, du*Bv[n]);
      y = fmaf(h[n], Cv[n], y);
    }
    y += __shfl_xor(y, 1);
    y += __shfl_xor(y, 2);
    if (g == 0){
      y = (y + uv*Dd) * (float)resb[row*DINNER + d];
      yb[row*DINNER + d] = (bf16)y;
    }
  }
}

// ---------------- host side ----------------
extern "C" void kernel_launch(void* const* d_in, const int* in_sizes, int n_in,
                              void* d_out, int out_size, void* d_ws, size_t ws_size,
                              hipStream_t stream){
  const float* x      = (const float*)d_in[0];
  const float* W_in   = (const float*)d_in[1];
  const float* conv_w = (const float*)d_in[2];
  const float* conv_b = (const float*)d_in[3];
  const float* W_xproj= (const float*)d_in[4];
  const float* W_dt   = (const float*)d_in[5];
  const float* b_dt   = (const float*)d_in[6];
  const float* A_log  = (const float*)d_in[7];
  const float* Dv     = (const float*)d_in[8];
  const float* W_out  = (const float*)d_in[9];
  float* out = (float*)d_out;

  uint8_t* wp = (uint8_t*)d_ws;
  auto alloc = [&](size_t bytes)->void*{ void* p = wp; wp += (bytes + 255) & ~(size_t)255; return p; };
  bf16*  xb     = (bf16*) alloc((size_t)MROWS*DMODEL*2);
  bf16*  WinT   = (bf16*) alloc((size_t)2*DINNER*DMODEL*2);   // (4096,1024)
  bf16*  WoutT  = (bf16*) alloc((size_t)DMODEL*DINNER*2);     // (1024,2048)
  bf16*  WxT    = (bf16*) alloc((size_t)128*DINNER*2);        // (128,2048) padded
  bf16*  WdtT   = (bf16*) alloc((size_t)DINNER*DTRANK*2);     // (2048,64)
  // updt (16MB) + scanPS (16MB) are contiguous; their 32MB span is reused as
  // GEMM-out split-K partials after scan phase3 (both dead by then).
  bf16*  updt   = (bf16*) alloc((size_t)MROWS*DINNER*2);      // u_pre bf16, then dt bf16
  float* scanPS = (float*)alloc((size_t)2*BSZ*NCHUNK*DSTATE*DINNER*4);  // 16MB
  float* Pbuf   = scanPS;
  float* Sbuf   = scanPS + (size_t)BSZ*NCHUNK*DSTATE*DINNER;
  float* xdbl_part = scanPS;                                  // 8 z-slices * 2 MB
  float* outpart   = (float*)updt;                            // 2 z-slices * 16 MB
  bf16*  resb   = (bf16*) alloc((size_t)MROWS*DINNER*2);      // silu(res)
  bf16*  ub     = (bf16*) alloc((size_t)MROWS*DINNER*2);      // conv+silu output
  float* xdbl   = (float*)alloc((size_t)MROWS*128*4);         // padded ld=128
  bf16*  dtlowb = (bf16*) alloc((size_t)MROWS*DTRANK*2);
  bf16*  yb     = (bf16*) alloc((size_t)MROWS*DINNER*2);

  // prep: cast x, all weight transposes in one launch
  k_cast_bf16<<<(MROWS*DMODEL/4 + 255)/256, 256, 0, stream>>>(x, xb, MROWS*DMODEL);
  k_transpose_all<<<4096+2048+256+128, dim3(32,8), 0, stream>>>(W_in, W_out, W_xproj, W_dt,
                                                                WinT, WoutT, WxT, WdtT);

  // GEMM-in: xr = x @ W_in, 128x256 tile, split epilogue -> u_pre (bf16) + silu(res) (bf16)
  k_gemm_bt<1,2><<<dim3(4096/256, 4096/128), 256, 0, stream>>>(xb, WinT, MROWS, 2*DINNER, DMODEL, nullptr, updt, resb, nullptr);
  // depthwise conv + silu -> ub (bf16)
  k_conv_silu<<<MROWS*DINNER/4/256, 256, 0, stream>>>(updt, conv_w, conv_b, ub);
  // x_dbl = u @ W_xproj  (N padded to 128), split-K=8 -> partials -> reduce (+dt_low cast)
  k_gemm_bt<0,1><<<dim3(1, 4096/128, 8), 256, 0, stream>>>(ub, WxT, MROWS, 128, DINNER, xdbl_part, nullptr, nullptr, nullptr);
  k_xdbl_reduce<<<(MROWS*128/4)/256, 256, 0, stream>>>(xdbl_part, xdbl, dtlowb);
  // dt = softplus(dt_low @ W_dt + b_dt) -> bf16 (overwrites u_pre buffer); single BK-64 iter
  k_gemm_bt<2,1><<<dim3(2048/128, 4096/128), 256, 0, stream>>>(dtlowb, WdtT, MROWS, DINNER, DTRANK, nullptr, updt, nullptr, b_dt);
  // chunked selective scan (4 states/thread)
  k_scan_phase1<<<BSZ*NCHUNK*DINNER*4/256, 256, 0, stream>>>(updt, ub, xdbl, A_log, Pbuf, Sbuf);
  k_scan_phase2<<<BSZ*DINNER*DSTATE/256, 256, 0, stream>>>(Pbuf, Sbuf);
  k_scan_phase3<<<BSZ*NCHUNK*DINNER*4/256, 256, 0, stream>>>(updt, ub, xdbl, A_log, Dv, Sbuf, resb, yb);
  // out = y @ W_out, split-K=2 (partials overwrite dead updt+scanPS region) -> reduce
  k_gemm_bt<0,1><<<dim3(1024/128, 4096/128, 2), 256, 0, stream>>>(yb, WoutT, MROWS, DMODEL, DINNER, outpart, nullptr, nullptr, nullptr);
  k_out_reduce<<<(MROWS*DMODEL/4)/256, 256, 0, stream>>>(outpart, out);
}

// Round 7
// 364.334 us; speedup vs baseline: 1.0851x; 1.0851x over previous
//
#include <hip/hip_runtime.h>
#include <cstdint>
#include <cstddef>

// ---------------- problem constants ----------------
#define DMODEL 1024
#define DINNER 2048
#define DSTATE 16
#define DCONV  4
#define DTRANK 64
#define BSZ    2
#define SEQL   2048
#define MROWS  (BSZ*SEQL)          // 4096
#define NCHUNK 32                  // scan chunks per sequence
#define CLEN   (SEQL/NCHUNK)       // 64

typedef __bf16 bf16;
typedef bf16  bf16x8 __attribute__((ext_vector_type(8)));
typedef bf16  bf16x4 __attribute__((ext_vector_type(4)));
typedef float floatx4 __attribute__((ext_vector_type(4)));

#define EPILDC 136   // padded epilogue LDS leading dim (272B = 4 mod 32 banks)

__device__ __forceinline__ float fsigmoid(float x){ return 1.f/(1.f+__expf(-x)); }
__device__ __forceinline__ float fsilu(float x){ return x*fsigmoid(x); }

__device__ __forceinline__ void gload_lds16(const void* g, void* l){
  __builtin_amdgcn_global_load_lds((__attribute__((address_space(1))) void*)g,
                                   (__attribute__((address_space(3))) void*)l,
                                   16, 0, 0);
}

// ---------------- elementwise cast fp32 -> bf16 (vec4) ----------------
__global__ void k_cast_bf16(const float* __restrict__ in, bf16* __restrict__ out, int n){
  int i = (blockIdx.x*blockDim.x + threadIdx.x)*4;
  if (i < n){
    float4 v = *(const float4*)(in + i);
    bf16x4 o; o[0]=(bf16)v.x; o[1]=(bf16)v.y; o[2]=(bf16)v.z; o[3]=(bf16)v.w;
    *(bf16x4*)(out + i) = o;
  }
}

// ---------------- all 4 weight transposes in ONE launch ----------------
// out[c][r] = in[r][c], zero-pad rows >= C (outR).  block (32,8)
__global__ void k_transpose_all(const float* __restrict__ W_in, const float* __restrict__ W_out,
                                const float* __restrict__ W_xproj, const float* __restrict__ W_dt,
                                bf16* __restrict__ WinT, bf16* __restrict__ WoutT,
                                bf16* __restrict__ WxT, bf16* __restrict__ WdtT){
  __shared__ float tile[32][33];
  int b = blockIdx.x;
  const float* in; bf16* out; int R, C, outR, nbx;
  if      (b < 4096)            { in=W_in;    out=WinT;  R=1024; C=4096; outR=4096; nbx=128; }
  else if (b < 4096+2048)       { b-=4096;    in=W_out;  out=WoutT; R=2048; C=1024; outR=1024; nbx=32; }
  else if (b < 4096+2048+256)   { b-=6144;    in=W_xproj;out=WxT;  R=2048; C=96;   outR=128;  nbx=4; }
  else                          { b-=6400;    in=W_dt;   out=WdtT; R=64;   C=2048; outR=2048; nbx=64; }
  int c0 = (b % nbx)*32, r0 = (b / nbx)*32;
  int tx = threadIdx.x, ty = threadIdx.y;
  #pragma unroll
  for (int ii=0; ii<4; ++ii){
    int r = r0 + ty + ii*8, c = c0 + tx;
    float v = 0.f;
    if (r < R && c < C) v = in[(size_t)r*C + c];
    tile[ty+ii*8][tx] = v;
  }
  __syncthreads();
  #pragma unroll
  for (int ii=0; ii<4; ++ii){
    int orow = c0 + ty + ii*8;   // original col
    int ocol = r0 + tx;          // original row
    if (orow < outR && ocol < R) out[(size_t)orow*R + ocol] = (bf16)tile[tx][ty+ii*8];
  }
}

// ---------------- bf16 MFMA GEMM: C = A(M,K) * B^T(N,K), 128x128 tile ----------------
// Double-buffered single-barrier K-loop, BK=32 (R3's 0-conflict swizzle):
//   per iter: barrier -> prefetch stage buf[p^1] -> ds_read buf[p] -> 16 MFMA.
//   The compiler's vmcnt(0)-before-s_barrier now drains loads issued one full
//   compute phase earlier (overlapped) instead of loads issued right before the
//   wait (R5's exposed drain). LDS: 4 x 8KB bufs, union with 34.8KB epilogue
//   region = 34816B -> same 3 blocks/CU as R5.
// Swizzle: 16B slot s of row r holds global chunk s ^ ((r>>1)&3); read side quad^((mrow>>1)&3).
// Split-K via gridDim.z (EPI0 partials to C0 + z*M*N).
// EPI 0: fp32 scattered dword stores (partials)
// EPI 1: GEMM-in: col<DINNER -> u_pre bf16 (C1); col>=DINNER -> silu -> resb (C2)
// EPI 2: dt: bf16(softplus(acc + bias[col])) -> C1, ldc=N
template<int EPI>
__global__ __launch_bounds__(256)
void k_gemm_bt(const bf16* __restrict__ A, const bf16* __restrict__ Bt,
               int M, int N, int K,
               float* __restrict__ C0, bf16* __restrict__ C1, bf16* __restrict__ C2,
               const float* __restrict__ bias){
  __shared__ bf16 lds[17408];            // 34816B: K-loop 4x4096-elem bufs / epilogue 128x136
  const int tid  = threadIdx.x;
  const int lane = tid & 63;
  const int wave = tid >> 6;
  const int quad = lane >> 4;
  const int mrow = lane & 15;
  const int wr = wave >> 1, wc = wave & 1;     // 2x2 wave grid, each 64x64
  const int bm = blockIdx.y * 128, bn = blockIdx.x * 128;
  const int Ks   = K / gridDim.z;
  const int kbeg = blockIdx.z * Ks;

  floatx4 acc[4][4];
  #pragma unroll
  for (int i=0;i<4;++i)
    #pragma unroll
    for (int j=0;j<4;++j) acc[i][j] = (floatx4){0.f,0.f,0.f,0.f};

  // staging: thread t -> row ar0 = t>>2 (+64 for second half), 16B slot t&3 holds
  // global chunk (t&3)^((ar0>>1)&3)
  const int ar0 = tid >> 2;
  const int kc  = ((tid & 3) ^ ((ar0 >> 1) & 3)) * 8;
  const bf16* Ag0 = A  + (size_t)(bm + ar0)      * K + kc;
  const bf16* Ag1 = A  + (size_t)(bm + ar0 + 64) * K + kc;
  const bf16* Bg0 = Bt + (size_t)(bn + ar0)      * K + kc;
  const bf16* Bg1 = Bt + (size_t)(bn + ar0 + 64) * K + kc;
  const int ksl = (mrow >> 1) & 3;             // read-side swizzle key

  auto stage = [&](int k0, int p){
    bf16* bA = lds + p*4096;
    bf16* bB = lds + 8192 + p*4096;
    gload_lds16(Ag0 + k0, bA + (size_t)tid*8);
    gload_lds16(Ag1 + k0, bA + (size_t)(256+tid)*8);
    gload_lds16(Bg0 + k0, bB + (size_t)tid*8);
    gload_lds16(Bg1 + k0, bB + (size_t)(256+tid)*8);
  };

  stage(kbeg, 0);
  int p = 0;
  for (int k0 = kbeg; k0 < kbeg + Ks; k0 += 32){
    __syncthreads();   // vmcnt(0): buf[p] staged; lgkmcnt(0): last iter's reads of buf[p^1] done
    if (k0 + 32 < kbeg + Ks) stage(k0 + 32, p ^ 1);
    const bf16* bA = lds + p*4096;
    const bf16* bB = lds + 8192 + p*4096;
    bf16x8 af[4], bfr[4];
    #pragma unroll
    for (int i=0;i<4;++i)
      af[i] = *(const bf16x8*)(bA + (wr*64 + i*16 + mrow)*32 + (quad ^ ksl)*8);
    #pragma unroll
    for (int j=0;j<4;++j)
      bfr[j] = *(const bf16x8*)(bB + (wc*64 + j*16 + mrow)*32 + (quad ^ ksl)*8);
    #pragma unroll
    for (int i=0;i<4;++i)
      #pragma unroll
      for (int j=0;j<4;++j)
        acc[i][j] = __builtin_amdgcn_mfma_f32_16x16x32_bf16(af[i], bfr[j], acc[i][j], 0,0,0);
    p ^= 1;
  }

  // ---- epilogue: lane holds D[row=quad*4+r][col=mrow] of each 16x16 tile ----
  if (EPI == 0){
    float* Cz = C0 + (size_t)blockIdx.z * M * N;
    #pragma unroll
    for (int i=0;i<4;++i){
      #pragma unroll
      for (int r=0;r<4;++r){
        int row = bm + wr*64 + i*16 + quad*4 + r;
        #pragma unroll
        for (int j=0;j<4;++j){
          int col = bn + wc*64 + j*16 + mrow;
          Cz[(size_t)row*N + col] = acc[i][j][r];
        }
      }
    }
  } else {
    __syncthreads();   // all waves done with K-loop LDS before overwrite
    // bf16 outputs: stage 128x128 tile in LDS (ld=EPILDC), then vectorized 16B stores
    const bool isres = (EPI == 1) && (bn >= DINNER);
    #pragma unroll
    for (int i=0;i<4;++i)
      #pragma unroll
      for (int r=0;r<4;++r){
        int lrow = wr*64 + i*16 + quad*4 + r;
        #pragma unroll
        for (int j=0;j<4;++j){
          int lcol = wc*64 + j*16 + mrow;
          float v = acc[i][j][r];
          float vt;
          if (EPI == 1) vt = isres ? fsilu(v) : v;
          else {
            float z = v + bias[bn + lcol];
            vt = (z > 20.f) ? z : log1pf(__expf(z));
          }
          lds[lrow*EPILDC + lcol] = (bf16)vt;
        }
      }
    __syncthreads();
    bf16* dst; int ldc;
    if (EPI == 1){ ldc = DINNER; dst = isres ? (C2 + (bn - DINNER)) : (C1 + bn); }
    else         { ldc = N;      dst = C1 + bn; }
    const int rr = tid >> 1, hh = (tid & 1)*64;
    #pragma unroll
    for (int i=0;i<8;++i)
      *(bf16x8*)(dst + (size_t)(bm + rr)*ldc + hh + i*8) =
        *(const bf16x8*)(lds + rr*EPILDC + hh + i*8);
  }
}

// ---------------- split-K reduce for x_dbl (+ fused dt_low bf16 slice cast) ----------------
__global__ void k_xdbl_reduce(const float* __restrict__ part, float* __restrict__ xdbl,
                              bf16* __restrict__ dtlowb){
  int t = blockIdx.x*blockDim.x + threadIdx.x;   // MROWS*128/4 threads
  int i4 = t*4;
  floatx4 acc = (floatx4){0.f,0.f,0.f,0.f};
  #pragma unroll
  for (int z=0; z<8; ++z)
    acc += *(const floatx4*)(part + (size_t)z*MROWS*128 + i4);
  *(floatx4*)(xdbl + i4) = acc;
  int r = i4 >> 7, c = i4 & 127;
  if (c < DTRANK){
    bf16x4 o; o[0]=(bf16)acc[0]; o[1]=(bf16)acc[1]; o[2]=(bf16)acc[2]; o[3]=(bf16)acc[3];
    *(bf16x4*)(dtlowb + (size_t)r*DTRANK + c) = o;
  }
}

// ---------------- split-K=2 reduce for out GEMM (fp32) ----------------
__global__ void k_out_reduce(const float* __restrict__ part, float* __restrict__ out){
  int i4 = (blockIdx.x*blockDim.x + threadIdx.x)*4;
  floatx4 a = *(const floatx4*)(part + i4);
  floatx4 b = *(const floatx4*)(part + (size_t)MROWS*DMODEL + i4);
  *(floatx4*)(out + i4) = a + b;
}

// ---------------- depthwise causal conv (width 4) + bias + SiLU -> bf16, vec4 in d ------
__global__ void k_conv_silu(const bf16* __restrict__ u_pre,
                            const float* __restrict__ conv_w,
                            const float* __restrict__ conv_b,
                            bf16* __restrict__ ub){
  int t   = blockIdx.x*blockDim.x + threadIdx.x;   // MROWS*DINNER/4
  int d4  = (t & (DINNER/4-1))*4;
  int row = t >> 9;
  int l   = row & (SEQL-1);
  float4 cb = *(const float4*)(conv_b + d4);
  float acc[4] = {cb.x, cb.y, cb.z, cb.w};
  float4 w0 = *(const float4*)(conv_w + (d4+0)*4);
  float4 w1 = *(const float4*)(conv_w + (d4+1)*4);
  float4 w2 = *(const float4*)(conv_w + (d4+2)*4);
  float4 w3 = *(const float4*)(conv_w + (d4+3)*4);
  float wk[4][4] = {{w0.x,w0.y,w0.z,w0.w},{w1.x,w1.y,w1.z,w1.w},
                    {w2.x,w2.y,w2.z,w2.w},{w3.x,w3.y,w3.z,w3.w}};
  #pragma unroll
  for (int k=0;k<4;++k){
    int lk = l + k - 3;
    if (lk >= 0){
      bf16x4 uv = *(const bf16x4*)(u_pre + (size_t)(row + k - 3)*DINNER + d4);
      #pragma unroll
      for (int j=0;j<4;++j) acc[j] += (float)uv[j] * wk[j][k];
    }
  }
  bf16x4 o;
  #pragma unroll
  for (int j=0;j<4;++j) o[j] = (bf16)fsilu(acc[j]);
  *(bf16x4*)(ub + (size_t)row*DINNER + d4) = o;
}

// ---------------- scan phase 1: 4 states/thread, per-chunk transfer (P, S) ----------------
__global__ void k_scan_phase1(const bf16* __restrict__ dt, const bf16* __restrict__ ub,
                              const float* __restrict__ x_dbl, const float* __restrict__ A_log,
                              float* __restrict__ Pbuf, float* __restrict__ Sbuf){
  int t  = blockIdx.x*blockDim.x + threadIdx.x;   // BSZ*NCHUNK*DINNER*4 = 524288
  int g  = t & 3;
  int d  = (t >> 2) & (DINNER-1);
  int bc = t >> 13;
  int c  = bc & (NCHUNK-1);
  int b  = bc >> 5;
  floatx4 alog = *(const floatx4*)(A_log + d*DSTATE + g*4);
  float an[4];
  #pragma unroll
  for (int n=0;n<4;++n) an[n] = -__expf(alog[n]);
  float P[4] = {1.f,1.f,1.f,1.f}, S[4] = {0.f,0.f,0.f,0.f};
  int base_row = b*SEQL + c*CLEN;
  for (int s=0;s<CLEN;++s){
    size_t row = base_row + s;
    float dtv = (float)dt[row*DINNER + d];
    float uv  = (float)ub[row*DINNER + d];
    float du  = dtv*uv;
    floatx4 Bv = *(const floatx4*)(x_dbl + row*128 + DTRANK + g*4);
    #pragma unroll
    for (int n=0;n<4;++n){
      float e = __expf(dtv*an[n]);
      P[n] *= e;
      S[n]  = fmaf(S[n], e, du*Bv[n]);
    }
  }
  size_t ob = ((size_t)bc*DINNER + d)*DSTATE + g*4;
  floatx4 Pv = {P[0],P[1],P[2],P[3]}, Sv = {S[0],S[1],S[2],S[3]};
  *(floatx4*)(Pbuf + ob) = Pv;
  *(floatx4*)(Sbuf + ob) = Sv;
}

// ---------------- scan phase 2: chunk combine over (b,d,n); Sbuf <- entry state ----------
__global__ void k_scan_phase2(const float* __restrict__ Pbuf, float* __restrict__ Sbuf){
  int t = blockIdx.x*blockDim.x + threadIdx.x;   // BSZ*DINNER*DSTATE = 65536
  int b   = t >> 15;
  int rem = t & 32767;           // d*16 + n
  float h = 0.f;
  for (int c=0;c<NCHUNK;++c){
    size_t ix = (size_t)(b*NCHUNK + c)*DINNER*DSTATE + rem;
    float p = Pbuf[ix], s = Sbuf[ix];
    Sbuf[ix] = h;                // entry state for chunk c
    h = fmaf(p, h, s);
  }
}

// ---------------- scan phase 3: replay with known entry state; fuse +u*D, *silu(res) -----
__global__ void k_scan_phase3(const bf16* __restrict__ dt, const bf16* __restrict__ ub,
                              const float* __restrict__ x_dbl, const float* __restrict__ A_log,
                              const float* __restrict__ Dvec, const float* __restrict__ Hin,
                              const bf16* __restrict__ resb, bf16* __restrict__ yb){
  int t  = blockIdx.x*blockDim.x + threadIdx.x;
  int g  = t & 3;
  int d  = (t >> 2) & (DINNER-1);
  int bc = t >> 13;
  int c  = bc & (NCHUNK-1);
  int b  = bc >> 5;
  floatx4 alog = *(const floatx4*)(A_log + d*DSTATE + g*4);
  float an[4];
  #pragma unroll
  for (int n=0;n<4;++n) an[n] = -__expf(alog[n]);
  floatx4 h = *(const floatx4*)(Hin + ((size_t)bc*DINNER + d)*DSTATE + g*4);
  float Dd = Dvec[d];
  int base_row = b*SEQL + c*CLEN;
  for (int s=0;s<CLEN;++s){
    size_t row = base_row + s;
    float dtv = (float)dt[row*DINNER + d];
    float uv  = (float)ub[row*DINNER + d];
    float du  = dtv*uv;
    floatx4 Bv = *(const floatx4*)(x_dbl + row*128 + DTRANK + g*4);
    floatx4 Cv = *(const floatx4*)(x_dbl + row*128 + DTRANK + DSTATE + g*4);
    float y = 0.f;
    #pragma unroll
    for (int n=0;n<4;++n){
      float e = __expf(dtv*an[n]);
      h[n] = fmaf(h[n], e, du*Bv[n]);
      y = fmaf(h[n], Cv[n], y);
    }
    y += __shfl_xor(y, 1);
    y += __shfl_xor(y, 2);
    if (g == 0){
      y = (y + uv*Dd) * (float)resb[row*DINNER + d];
      yb[row*DINNER + d] = (bf16)y;
    }
  }
}

// ---------------- host side ----------------
extern "C" void kernel_launch(void* const* d_in, const int* in_sizes, int n_in,
                              void* d_out, int out_size, void* d_ws, size_t ws_size,
                              hipStream_t stream){
  const float* x      = (const float*)d_in[0];
  const float* W_in   = (const float*)d_in[1];
  const float* conv_w = (const float*)d_in[2];
  const float* conv_b = (const float*)d_in[3];
  const float* W_xproj= (const float*)d_in[4];
  const float* W_dt   = (const float*)d_in[5];
  const float* b_dt   = (const float*)d_in[6];
  const float* A_log  = (const float*)d_in[7];
  const float* Dv     = (const float*)d_in[8];
  const float* W_out  = (const float*)d_in[9];
  float* out = (float*)d_out;

  uint8_t* wp = (uint8_t*)d_ws;
  auto alloc = [&](size_t bytes)->void*{ void* p = wp; wp += (bytes + 255) & ~(size_t)255; return p; };
  bf16*  xb     = (bf16*) alloc((size_t)MROWS*DMODEL*2);
  bf16*  WinT   = (bf16*) alloc((size_t)2*DINNER*DMODEL*2);   // (4096,1024)
  bf16*  WoutT  = (bf16*) alloc((size_t)DMODEL*DINNER*2);     // (1024,2048)
  bf16*  WxT    = (bf16*) alloc((size_t)128*DINNER*2);        // (128,2048) padded
  bf16*  WdtT   = (bf16*) alloc((size_t)DINNER*DTRANK*2);     // (2048,64)
  // updt (16MB) + scanPS (16MB) are contiguous; their 32MB span is reused as
  // GEMM-out split-K partials after scan phase3 (both dead by then).
  bf16*  updt   = (bf16*) alloc((size_t)MROWS*DINNER*2);      // u_pre bf16, then dt bf16
  float* scanPS = (float*)alloc((size_t)2*BSZ*NCHUNK*DSTATE*DINNER*4);  // 16MB
  float* Pbuf   = scanPS;
  float* Sbuf   = scanPS + (size_t)BSZ*NCHUNK*DSTATE*DINNER;
  float* xdbl_part = scanPS;                                  // 8 z-slices * 2 MB
  float* outpart   = (float*)updt;                            // 2 z-slices * 16 MB
  bf16*  resb   = (bf16*) alloc((size_t)MROWS*DINNER*2);      // silu(res)
  bf16*  ub     = (bf16*) alloc((size_t)MROWS*DINNER*2);      // conv+silu output
  float* xdbl   = (float*)alloc((size_t)MROWS*128*4);         // padded ld=128
  bf16*  dtlowb = (bf16*) alloc((size_t)MROWS*DTRANK*2);
  bf16*  yb     = (bf16*) alloc((size_t)MROWS*DINNER*2);

  // prep: cast x, all weight transposes in one launch
  k_cast_bf16<<<(MROWS*DMODEL/4 + 255)/256, 256, 0, stream>>>(x, xb, MROWS*DMODEL);
  k_transpose_all<<<4096+2048+256+128, dim3(32,8), 0, stream>>>(W_in, W_out, W_xproj, W_dt,
                                                                WinT, WoutT, WxT, WdtT);

  // GEMM-in: xr = x @ W_in, split epilogue -> u_pre (bf16) + silu(res) (bf16)
  k_gemm_bt<1><<<dim3(4096/128, 4096/128), 256, 0, stream>>>(xb, WinT, MROWS, 2*DINNER, DMODEL, nullptr, updt, resb, nullptr);
  // depthwise conv + silu -> ub (bf16)
  k_conv_silu<<<MROWS*DINNER/4/256, 256, 0, stream>>>(updt, conv_w, conv_b, ub);
  // x_dbl = u @ W_xproj  (N padded to 128), split-K=8 -> partials -> reduce (+dt_low cast)
  k_gemm_bt<0><<<dim3(1, 4096/128, 8), 256, 0, stream>>>(ub, WxT, MROWS, 128, DINNER, xdbl_part, nullptr, nullptr, nullptr);
  k_xdbl_reduce<<<(MROWS*128/4)/256, 256, 0, stream>>>(xdbl_part, xdbl, dtlowb);
  // dt = softplus(dt_low @ W_dt + b_dt) -> bf16 (overwrites u_pre buffer)
  k_gemm_bt<2><<<dim3(2048/128, 4096/128), 256, 0, stream>>>(dtlowb, WdtT, MROWS, DINNER, DTRANK, nullptr, updt, nullptr, b_dt);
  // chunked selective scan (4 states/thread)
  k_scan_phase1<<<BSZ*NCHUNK*DINNER*4/256, 256, 0, stream>>>(updt, ub, xdbl, A_log, Pbuf, Sbuf);
  k_scan_phase2<<<BSZ*DINNER*DSTATE/256, 256, 0, stream>>>(Pbuf, Sbuf);
  k_scan_phase3<<<BSZ*NCHUNK*DINNER*4/256, 256, 0, stream>>>(updt, ub, xdbl, A_log, Dv, Sbuf, resb, yb);
  // out = y @ W_out, split-K=2 (partials overwrite dead updt+scanPS region) -> reduce
  k_gemm_bt<0><<<dim3(1024/128, 4096/128, 2), 256, 0, stream>>>(yb, WoutT, MROWS, DMODEL, DINNER, outpart, nullptr, nullptr, nullptr);
  k_out_reduce<<<(MROWS*DMODEL/4)/256, 256, 0, stream>>>(outpart, out);
}